// Round 5
// baseline (1908.841 us; speedup 1.0000x reference)
//
#include <hip/hip_runtime.h>
#include <math.h>

#define NB_IN   128
#define NBINS   39
#define NLM     400
#define NZO     512
#define NPAIR   780
#define NPACK   5530
#define TWOB    40
#define PI_D    3.14159265358979323846
#define SCALING 0.008164965809277261

__host__ __device__ __forceinline__ int loffd(int l){ return l*(4*l*l + 3*l - 1)/6; }

__device__ __forceinline__ int lidx(int lm){
  int l = (int)sqrtf((float)lm);
  while ((l+1)*(l+1) <= lm) ++l;
  while (l*l > lm) --l;
  return l;
}

// Wigner little-d via Jacobi sum (one-shot, used by cheap kernels only)
__device__ double wigner_d(int l, int m, int n, double beta, const double* lg){
  double cb = cos(0.5*beta), sb = sin(0.5*beta);
  double lcb = log(cb), lsb = log(sb);
  double pref = 0.5*(lg[l+m]+lg[l-m]+lg[l+n]+lg[l-n]);
  int s0 = 0 > (n-m) ? 0 : (n-m);
  int s1 = (l+n) < (l-m) ? (l+n) : (l-m);
  double val = 0.0;
  for (int s = s0; s <= s1; ++s){
    double c = pref - (lg[l+n-s]+lg[s]+lg[m-n+s]+lg[l-m-s]);
    double t = exp(c + (double)(2*l+n-m-2*s)*lcb + (double)(m-n+2*s)*lsb);
    val += ((m-n+s)&1) ? -t : t;
  }
  return val;
}

// fast Wigner: 2 log + 1 exp + ratio recurrence over s (fp64)
__device__ double wigner_fast(int l, int m, int n, double beta, const double* lg){
  double cb = cos(0.5*beta), sb = sin(0.5*beta);
  double lcb = log(cb), lsb = log(sb);
  double pref = 0.5*(lg[l+m]+lg[l-m]+lg[l+n]+lg[l-n]);
  int s0 = 0 > (n-m) ? 0 : (n-m);
  int s1 = (l+n) < (l-m) ? (l+n) : (l-m);
  double ratio = (sb*sb)/(cb*cb);
  double t = exp(pref - (lg[l+n-s0]+lg[s0]+lg[m-n+s0]+lg[l-m-s0])
               + (double)(2*l+n-m-2*s0)*lcb + (double)(m-n+2*s0)*lsb);
  double sgn = ((m-n+s0)&1) ? -1.0 : 1.0;
  double acc = 0.0;
  for (int s = s0; s <= s1; ++s){
    acc += sgn*t;
    sgn = -sgn;
    t *= ratio * ((double)((l+n-s)*(l-m-s)) / (double)((s+1)*(m-n+s+1)));
  }
  return acc;
}

// ---- constants -------------------------------------------------------
__global__ void k_init(double* lg, double* wq, int* ridx, int* pidx){
  int t = threadIdx.x;  // 128
  if (t == 0){
    lg[0] = 0.0; double acc = 0.0;
    for (int k = 1; k <= 40; ++k){ acc += log((double)k); lg[k] = acc; }
  }
  if (t == 1){
    int off = 0;
    for (int l = 0; l < 20; ++l)
      for (int mj = 0; mj <= l; ++mj)
        for (int njs = 19-l; njs <= 19+l; ++njs){
          ridx[off] = mj | (njs<<8) | (l<<16);
          pidx[off] = mj*39 + njs;
          ++off;
        }
  }
  double theta = PI_D*(2*t+1)/256.0;
  double s = 0.0;
  for (int k = 0; k < 64; ++k) s += sin((2*k+1)*theta)/(double)(2*k+1);
  wq[t] = (2.0/64.0)*sin(theta)*s;
}

__global__ void k_wsyn(float2* wsyn){
  for (int idx = threadIdx.x; idx < 1560+800; idx += 256){
    double ang;
    if (idx < 1560){
      int njs = idx/40, g = idx%40;
      ang = 2.0*PI_D*(double)(njs-19)*(double)g/40.0;
    } else {
      int r = idx-1560; int mj = r/40, a = r%40;
      ang = 2.0*PI_D*(double)mj*(double)a/40.0;
    }
    wsyn[idx] = make_float2((float)cos(ang), (float)sin(ang));
  }
}

// w_s2: thread = (lm, 16-b chunk)
__global__ void k_ws2(float* w_s2, const double* lg, const double* wq){
  int tid = blockIdx.x*256 + threadIdx.x;
  if (tid >= 400*8) return;
  int lm = tid >> 3, bc = tid & 7;
  int l = lidx(lm); int m = lm - l*l - l;
  for (int j = 0; j < 16; ++j){
    int b = bc*16 + j;
    double beta = PI_D*(2*b+1)/256.0;
    w_s2[b*NLM + lm] = (float)(wigner_fast(l, m, 0, beta, lg) * wq[b]);
  }
}

// dinv2 rows b=0..19, l-major packed
__global__ void k_dinv2(float* dinv2, const int* ridx, const double* lg){
  int k = blockIdx.x*256 + threadIdx.x;
  if (k >= NPACK) return;
  int info = ridx[k];
  int mj = info & 255, n = ((info>>8)&255) - 19, l = info>>16;
  for (int b = 0; b < 20; ++b){
    double beta = PI_D*(2*b+1)/80.0;
    dinv2[b*NPACK + k] = (float)((double)(2*l+1) * wigner_fast(l, mj, n, beta, lg));
  }
}

// mirror rows b=20..39 via d^l_{m,n}(pi-b) = (-1)^{l+m} d^l_{m,-n}(b)
__global__ void k_dmir(float* dinv2, const int* ridx){
  int tid = blockIdx.x*256 + threadIdx.x;
  if (tid >= 20*NPACK) return;
  int bb = tid / NPACK, k = tid % NPACK;
  int info = ridx[k];
  int mj = info & 255, njs = (info>>8)&255, l = info>>16;
  int srck = loffd(l) + mj*(2*l+1) + (l - (njs-19));
  float v = dinv2[(19-bb)*NPACK + srck];
  dinv2[(20+bb)*NPACK + k] = ((l+mj)&1) ? -v : v;
}

__global__ void k_Fc(float2* Fc, const double* lg){
  int tid = blockIdx.x*256 + threadIdx.x;
  if (tid >= 24*NLM) return;
  int p = tid / NLM, lm = tid % NLM;
  int l = lidx(lm); int m = lm - l*l - l;
  double beta = PI_D*(double)(p/8 + 1)/24.0;
  double alpha = (double)(p%8)*(PI_D/4.0);
  double d = wigner_d(l, m, 0, beta, lg);
  double a = (double)m*alpha;            // conj(F_k)
  Fc[tid] = make_float2((float)(d*cos(a)), (float)(d*sin(a)));
}

// ycT[o][i][lm] = conj(y)*SCALING
__global__ void k_yc(const float* ker, const float2* Fc, float2* ycT){
  int tid = blockIdx.x*256 + threadIdx.x;
  if (tid >= NLM*NZO) return;
  int lm = tid / 512, io = tid % 512;
  int i = io >> 5, o = io & 31;
  float2 acc = make_float2(0.f, 0.f);
  for (int p = 0; p < 24; ++p){
    float kv = ker[io*24 + p];
    float2 f = Fc[p*NLM + lm];
    acc.x += kv*f.x; acc.y += kv*f.y;
  }
  acc.x *= (float)SCALING; acc.y *= (float)SCALING;
  ycT[((size_t)(o*16 + i))*NLM + lm] = acc;
}

// ---- pipeline --------------------------------------------------------
// xf[mj][b][zi] via per-lane phase recurrence
__global__ __launch_bounds__(256) void k_dft(const float* x, float2* xf){
  __shared__ float rows[4][128];
  int t = threadIdx.x, g = t >> 6, lane = t & 63;
  int r = blockIdx.x*4 + g;
  int zi = r & 255, b = r >> 8;
  const float* xr = x + ((size_t)zi*128 + b)*128;
  rows[g][lane]    = xr[lane];
  rows[g][lane+64] = xr[lane+64];
  __syncthreads();
  if (lane < NBINS){
    int m = lane - 19;
    float ang = -2.0f*(float)PI_D*(float)m/128.0f;
    float sn, cs; sincosf(ang, &sn, &cs);
    float wr = 1.f, wi = 0.f;
    float2 acc = make_float2(0.f, 0.f);
    const float* rw = rows[g];
    #pragma unroll 8
    for (int a = 0; a < 128; ++a){
      float v = rw[a];
      acc.x += v*wr; acc.y += v*wi;
      float nr = wr*cs - wi*sn;
      wi = wr*sn + wi*cs; wr = nr;
    }
    xf[((size_t)lane*128 + b)*256 + zi] = acc;
  }
}

// partial beta-contraction: xlp[c][lm][zi], c = 32-b chunk
__global__ void k_xlp(const float2* xf, const float* w_s2, float2* xlp){
  int lm = blockIdx.x, c = blockIdx.y, zi = threadIdx.x;
  int l = lidx(lm); int m = lm - l*l - l;
  int bin = m + 19;
  float2 acc = make_float2(0.f, 0.f);
  for (int b = c*32; b < c*32+32; ++b){
    float w = w_s2[b*NLM + lm];
    float2 v = xf[((size_t)bin*128 + b)*256 + zi];
    acc.x += w*v.x; acc.y += w*v.y;
  }
  xlp[((size_t)(c*NLM + lm))*256 + zi] = acc;
}

// sum chunks -> xlT[zi][lm]
__global__ void k_xlsum(const float2* xlp, float2* xlT){
  int lm = blockIdx.x, zi = threadIdx.x;
  float2 s = make_float2(0.f, 0.f);
  for (int c = 0; c < 4; ++c){
    float2 v = xlp[((size_t)(c*NLM + lm))*256 + zi];
    s.x += v.x; s.y += v.y;
  }
  xlT[(size_t)zi*NLM + lm] = s;
}

// zl2[zo][k] (l-major packed), fully coalesced
__global__ void k_zl2(const float2* xlT, const float2* ycT, const int* ridx, float2* zl2){
  int tid = blockIdx.x*256 + threadIdx.x;
  int zo = tid / NPACK, k = tid % NPACK;
  int info = ridx[k];
  int mj = info & 255, njs = (info>>8)&255, l = info>>16;
  int z = zo >> 5, o = zo & 31;
  int lmm = l*l + l + mj;
  int lmn = l*l + l + (njs - 19);
  float2 acc = make_float2(0.f, 0.f);
  for (int i = 0; i < 16; ++i){
    float2 a  = xlT[(size_t)(z*16 + i)*NLM + lmm];
    float2 bb = ycT[(size_t)(o*16 + i)*NLM + lmn];
    acc.x += a.x*bb.x - a.y*bb.y;
    acc.y += a.x*bb.y + a.y*bb.x;
  }
  zl2[tid] = acc;
}

// fused synthesis: one block per zo, loop over all 40 b
__global__ __launch_bounds__(256) void k_syn4(const float2* zl2, const float* dinv2,
                                              const int* pidx, const float2* wsyn,
                                              const float* bias, float* out){
  __shared__ float2 zS[NPACK];              // 44.24 KB
  __shared__ float2 Cs[NPAIR];              // 6.24 KB
  __shared__ __align__(16) float2 Gs[800];  // 6.4 KB
  __shared__ __align__(16) float2 Wns[1560];// 12.48 KB
  __shared__ __align__(16) float2 Wms[800]; // 6.4 KB

  int zo = blockIdx.x;
  int o = zo & 31;
  int t = threadIdx.x;

  // prologue: stage zl2 row, weights, zero Cs
  const float2* zrow = zl2 + (size_t)zo*NPACK;
  for (int k = t; k < NPACK; k += 256) zS[k] = zrow[k];
  for (int idx = t; idx < 1560; idx += 256) Wns[idx] = wsyn[idx];
  for (int idx = t; idx < 800;  idx += 256) Wms[idx] = wsyn[1560+idx];
  for (int p = t; p < NPAIR; p += 256) Cs[p] = make_float2(0.f, 0.f);
  __syncthreads();

  float bv = bias[o];
  float* obase = out + (size_t)zo*40*1600;

  for (int b = 0; b < 40; ++b){
    // ---- stage 1: Cs[pair] += dinv2[b][k] * zS[k] (LDS atomic scatter) ----
    const float* drow = dinv2 + (size_t)b*NPACK;
    for (int k = t; k < NPACK; k += 256){
      float d = drow[k];
      int p = pidx[k];
      float2 z = zS[k];
      atomicAdd(&Cs[p].x, d*z.x);
      atomicAdd(&Cs[p].y, d*z.y);
    }
    __syncthreads();

    // ---- stage 2: G[mj][g] = sum_n C[mj][n] Wn[n][g] ----
    for (int idx = t; idx < 800; idx += 256){
      int mj = idx/40, g = idx%40;
      const float2* crow = Cs + mj*39;
      const float2* wg = Wns + g;
      float2 acc = make_float2(0.f, 0.f);
      #pragma unroll 13
      for (int nj = 0; nj < 39; ++nj){
        float2 c = crow[nj]; float2 w = wg[nj*40];
        acc.x += c.x*w.x - c.y*w.y;
        acc.y += c.x*w.y + c.y*w.x;
      }
      Gs[idx] = acc;
    }
    __syncthreads();

    // ---- stage 3: out[a][g] = G0[g].x + 2*sum_{mj>=1} Re(G*Wm) + bias ----
    // (also zero Cs for next b: stage 3 reads only Gs)
    float* orow = obase + b*1600;
    for (int idx = t; idx < 1600; idx += 256){
      int a = idx/40, g = idx%40;
      const float2* gcol = Gs + g;
      const float2* wa = Wms + a;
      float acc = 0.f;
      #pragma unroll 19
      for (int mj = 1; mj < 20; ++mj){
        float2 gv = gcol[mj*40];
        float2 w  = wa[mj*40];
        acc += gv.x*w.x - gv.y*w.y;
      }
      orow[idx] = Gs[g].x + 2.f*acc + bv;
    }
    for (int p = t; p < NPAIR; p += 256) Cs[p] = make_float2(0.f, 0.f);
    __syncthreads();
  }
}

extern "C" void kernel_launch(void* const* d_in, const int* in_sizes, int n_in,
                              void* d_out, int out_size, void* d_ws, size_t ws_size,
                              hipStream_t stream) {
  const float* x    = (const float*)d_in[0];
  const float* ker  = (const float*)d_in[1];
  const float* bias = (const float*)d_in[2];
  float* out = (float*)d_out;

  char* ws = (char*)d_ws;
  size_t cur = 0;
  auto alloc = [&](size_t bytes)->char*{
    char* p = ws + cur;
    cur += (bytes + 255) & ~(size_t)255;
    return p;
  };
  double* lg    = (double*)alloc(64*8);
  double* wq    = (double*)alloc(128*8);
  int*    ridx  = (int*)   alloc(NPACK*4);
  int*    pidx  = (int*)   alloc(NPACK*4);
  float2* wsyn  = (float2*)alloc((size_t)2360*8);
  float*  w_s2  = (float*) alloc((size_t)NB_IN*NLM*4);
  float*  dinv2 = (float*) alloc((size_t)TWOB*NPACK*4);
  float2* Fc    = (float2*)alloc((size_t)24*NLM*8);
  float2* ycT   = (float2*)alloc((size_t)512*400*8);
  float2* xf    = (float2*)alloc((size_t)NBINS*128*256*8);
  float2* xlp   = (float2*)alloc((size_t)4*NLM*256*8);
  float2* xlT   = (float2*)alloc((size_t)256*NLM*8);
  float2* zl2   = (float2*)alloc((size_t)NZO*NPACK*8);
  (void)ws_size; (void)in_sizes; (void)n_in; (void)out_size;

  k_init <<<1, 128, 0, stream>>>(lg, wq, ridx, pidx);
  k_wsyn <<<1, 256, 0, stream>>>(wsyn);
  k_ws2  <<<13, 256, 0, stream>>>(w_s2, lg, wq);
  k_dinv2<<<22, 256, 0, stream>>>(dinv2, ridx, lg);
  k_dmir <<<(20*NPACK + 255)/256, 256, 0, stream>>>(dinv2, ridx);
  k_Fc   <<<38, 256, 0, stream>>>(Fc, lg);
  k_yc   <<<800, 256, 0, stream>>>(ker, Fc, ycT);

  k_dft  <<<(256*128)/4, 256, 0, stream>>>(x, xf);
  k_xlp  <<<dim3(NLM, 4), 256, 0, stream>>>(xf, w_s2, xlp);
  k_xlsum<<<NLM, 256, 0, stream>>>(xlp, xlT);
  k_zl2  <<<(NZO*NPACK)/256, 256, 0, stream>>>(xlT, ycT, ridx, zl2);
  k_syn4 <<<NZO, 256, 0, stream>>>(zl2, dinv2, pidx, wsyn, bias, out);
}

// Round 6
// 807.534 us; speedup vs baseline: 2.3638x; 2.3638x over previous
//
#include <hip/hip_runtime.h>
#include <math.h>

#define NB_IN   128
#define NBINS   39
#define NLM     400
#define NZO     512
#define NPAIR   780
#define NPACK   5530
#define TWOB    40
#define PI_D    3.14159265358979323846
#define SCALING 0.008164965809277261

__host__ __device__ __forceinline__ int loffd(int l){ return l*(4*l*l + 3*l - 1)/6; }

__device__ __forceinline__ int lidx(int lm){
  int l = (int)sqrtf((float)lm);
  while ((l+1)*(l+1) <= lm) ++l;
  while (l*l > lm) --l;
  return l;
}

// Wigner little-d via Jacobi sum (one-shot, used by cheap kernels only)
__device__ double wigner_d(int l, int m, int n, double beta, const double* lg){
  double cb = cos(0.5*beta), sb = sin(0.5*beta);
  double lcb = log(cb), lsb = log(sb);
  double pref = 0.5*(lg[l+m]+lg[l-m]+lg[l+n]+lg[l-n]);
  int s0 = 0 > (n-m) ? 0 : (n-m);
  int s1 = (l+n) < (l-m) ? (l+n) : (l-m);
  double val = 0.0;
  for (int s = s0; s <= s1; ++s){
    double c = pref - (lg[l+n-s]+lg[s]+lg[m-n+s]+lg[l-m-s]);
    double t = exp(c + (double)(2*l+n-m-2*s)*lcb + (double)(m-n+2*s)*lsb);
    val += ((m-n+s)&1) ? -t : t;
  }
  return val;
}

// fast Wigner: 2 log + 1 exp + ratio recurrence over s (fp64)
__device__ double wigner_fast(int l, int m, int n, double beta, const double* lg){
  double cb = cos(0.5*beta), sb = sin(0.5*beta);
  double lcb = log(cb), lsb = log(sb);
  double pref = 0.5*(lg[l+m]+lg[l-m]+lg[l+n]+lg[l-n]);
  int s0 = 0 > (n-m) ? 0 : (n-m);
  int s1 = (l+n) < (l-m) ? (l+n) : (l-m);
  double ratio = (sb*sb)/(cb*cb);
  double t = exp(pref - (lg[l+n-s0]+lg[s0]+lg[m-n+s0]+lg[l-m-s0])
               + (double)(2*l+n-m-2*s0)*lcb + (double)(m-n+2*s0)*lsb);
  double sgn = ((m-n+s0)&1) ? -1.0 : 1.0;
  double acc = 0.0;
  for (int s = s0; s <= s1; ++s){
    acc += sgn*t;
    sgn = -sgn;
    t *= ratio * ((double)((l+n-s)*(l-m-s)) / (double)((s+1)*(m-n+s+1)));
  }
  return acc;
}

// ---- constants -------------------------------------------------------
__global__ void k_init(double* lg, double* wq, int* ridx, int* psort, int* npre){
  int t = threadIdx.x;  // 128
  if (t == 0){
    lg[0] = 0.0; double acc = 0.0;
    for (int k = 1; k <= 40; ++k){ acc += log((double)k); lg[k] = acc; }
  }
  if (t == 1){
    int off = 0;
    for (int l = 0; l < 20; ++l)
      for (int mj = 0; mj <= l; ++mj)
        for (int njs = 19-l; njs <= 19+l; ++njs)
          ridx[off++] = mj | (njs<<8) | (l<<16);
  }
  if (t == 2){
    int cnt[20], pos[20];
    for (int i = 0; i < 20; ++i) cnt[i] = 0;
    for (int p = 0; p < NPAIR; ++p){
      int mj = p/39, d = p%39 - 19, ad = d<0?-d:d;
      int lm_ = mj > ad ? mj : ad; cnt[lm_]++;
    }
    int run = 0;
    for (int l = 0; l < 20; ++l){ pos[l] = run; run += cnt[l]; npre[l] = run; }
    for (int p = 0; p < NPAIR; ++p){
      int mj = p/39, njs = p%39, d = njs - 19, ad = d<0?-d:d;
      int lm_ = mj > ad ? mj : ad;
      psort[pos[lm_]++] = mj | (njs<<8);
    }
  }
  double theta = PI_D*(2*t+1)/256.0;
  double s = 0.0;
  for (int k = 0; k < 64; ++k) s += sin((2*k+1)*theta)/(double)(2*k+1);
  wq[t] = (2.0/64.0)*sin(theta)*s;
}

__global__ void k_wsyn(float2* wsyn){
  for (int idx = threadIdx.x; idx < 1560+800; idx += 256){
    double ang;
    if (idx < 1560){
      int njs = idx/40, g = idx%40;
      ang = 2.0*PI_D*(double)(njs-19)*(double)g/40.0;
    } else {
      int r = idx-1560; int mj = r/40, a = r%40;
      ang = 2.0*PI_D*(double)mj*(double)a/40.0;
    }
    wsyn[idx] = make_float2((float)cos(ang), (float)sin(ang));
  }
}

// w_s2: thread = (lm, 16-b chunk)
__global__ void k_ws2(float* w_s2, const double* lg, const double* wq){
  int tid = blockIdx.x*256 + threadIdx.x;
  if (tid >= 400*8) return;
  int lm = tid >> 3, bc = tid & 7;
  int l = lidx(lm); int m = lm - l*l - l;
  for (int j = 0; j < 16; ++j){
    int b = bc*16 + j;
    double beta = PI_D*(2*b+1)/256.0;
    w_s2[b*NLM + lm] = (float)(wigner_fast(l, m, 0, beta, lg) * wq[b]);
  }
}

// dinv2 rows b=0..19, l-major packed
__global__ void k_dinv2(float* dinv2, const int* ridx, const double* lg){
  int k = blockIdx.x*256 + threadIdx.x;
  if (k >= NPACK) return;
  int info = ridx[k];
  int mj = info & 255, n = ((info>>8)&255) - 19, l = info>>16;
  for (int b = 0; b < 20; ++b){
    double beta = PI_D*(2*b+1)/80.0;
    dinv2[b*NPACK + k] = (float)((double)(2*l+1) * wigner_fast(l, mj, n, beta, lg));
  }
}

// mirror rows b=20..39 via d^l_{m,n}(pi-b) = (-1)^{l+m} d^l_{m,-n}(b)
__global__ void k_dmir(float* dinv2, const int* ridx){
  int tid = blockIdx.x*256 + threadIdx.x;
  if (tid >= 20*NPACK) return;
  int bb = tid / NPACK, k = tid % NPACK;
  int info = ridx[k];
  int mj = info & 255, njs = (info>>8)&255, l = info>>16;
  int srck = loffd(l) + mj*(2*l+1) + (l - (njs-19));
  float v = dinv2[(19-bb)*NPACK + srck];
  dinv2[(20+bb)*NPACK + k] = ((l+mj)&1) ? -v : v;
}

__global__ void k_Fc(float2* Fc, const double* lg){
  int tid = blockIdx.x*256 + threadIdx.x;
  if (tid >= 24*NLM) return;
  int p = tid / NLM, lm = tid % NLM;
  int l = lidx(lm); int m = lm - l*l - l;
  double beta = PI_D*(double)(p/8 + 1)/24.0;
  double alpha = (double)(p%8)*(PI_D/4.0);
  double d = wigner_d(l, m, 0, beta, lg);
  double a = (double)m*alpha;            // conj(F_k)
  Fc[tid] = make_float2((float)(d*cos(a)), (float)(d*sin(a)));
}

// ycT[o][i][lm] = conj(y)*SCALING
__global__ void k_yc(const float* ker, const float2* Fc, float2* ycT){
  int tid = blockIdx.x*256 + threadIdx.x;
  if (tid >= NLM*NZO) return;
  int lm = tid / 512, io = tid % 512;
  int i = io >> 5, o = io & 31;
  float2 acc = make_float2(0.f, 0.f);
  for (int p = 0; p < 24; ++p){
    float kv = ker[io*24 + p];
    float2 f = Fc[p*NLM + lm];
    acc.x += kv*f.x; acc.y += kv*f.y;
  }
  acc.x *= (float)SCALING; acc.y *= (float)SCALING;
  ycT[((size_t)(o*16 + i))*NLM + lm] = acc;
}

// ---- pipeline --------------------------------------------------------
// xf[mj][b][zi] via per-lane phase recurrence
__global__ __launch_bounds__(256) void k_dft(const float* x, float2* xf){
  __shared__ float rows[4][128];
  int t = threadIdx.x, g = t >> 6, lane = t & 63;
  int r = blockIdx.x*4 + g;
  int zi = r & 255, b = r >> 8;
  const float* xr = x + ((size_t)zi*128 + b)*128;
  rows[g][lane]    = xr[lane];
  rows[g][lane+64] = xr[lane+64];
  __syncthreads();
  if (lane < NBINS){
    int m = lane - 19;
    float ang = -2.0f*(float)PI_D*(float)m/128.0f;
    float sn, cs; sincosf(ang, &sn, &cs);
    float wr = 1.f, wi = 0.f;
    float2 acc = make_float2(0.f, 0.f);
    const float* rw = rows[g];
    #pragma unroll 8
    for (int a = 0; a < 128; ++a){
      float v = rw[a];
      acc.x += v*wr; acc.y += v*wi;
      float nr = wr*cs - wi*sn;
      wi = wr*sn + wi*cs; wr = nr;
    }
    xf[((size_t)lane*128 + b)*256 + zi] = acc;
  }
}

// partial beta-contraction: xlp[c][lm][zi], c = 32-b chunk
__global__ void k_xlp(const float2* xf, const float* w_s2, float2* xlp){
  int lm = blockIdx.x, c = blockIdx.y, zi = threadIdx.x;
  int l = lidx(lm); int m = lm - l*l - l;
  int bin = m + 19;
  float2 acc = make_float2(0.f, 0.f);
  for (int b = c*32; b < c*32+32; ++b){
    float w = w_s2[b*NLM + lm];
    float2 v = xf[((size_t)bin*128 + b)*256 + zi];
    acc.x += w*v.x; acc.y += w*v.y;
  }
  xlp[((size_t)(c*NLM + lm))*256 + zi] = acc;
}

// sum chunks -> xlT[zi][lm]
__global__ void k_xlsum(const float2* xlp, float2* xlT){
  int lm = blockIdx.x, zi = threadIdx.x;
  float2 s = make_float2(0.f, 0.f);
  for (int c = 0; c < 4; ++c){
    float2 v = xlp[((size_t)(c*NLM + lm))*256 + zi];
    s.x += v.x; s.y += v.y;
  }
  xlT[(size_t)zi*NLM + lm] = s;
}

// zl2[zo][k] (l-major packed), fully coalesced
__global__ void k_zl2(const float2* xlT, const float2* ycT, const int* ridx, float2* zl2){
  int tid = blockIdx.x*256 + threadIdx.x;
  int zo = tid / NPACK, k = tid % NPACK;
  int info = ridx[k];
  int mj = info & 255, njs = (info>>8)&255, l = info>>16;
  int z = zo >> 5, o = zo & 31;
  int lmm = l*l + l + mj;
  int lmn = l*l + l + (njs - 19);
  float2 acc = make_float2(0.f, 0.f);
  for (int i = 0; i < 16; ++i){
    float2 a  = xlT[(size_t)(z*16 + i)*NLM + lmm];
    float2 bb = ycT[(size_t)(o*16 + i)*NLM + lmn];
    acc.x += a.x*bb.x - a.y*bb.y;
    acc.y += a.x*bb.y + a.y*bb.x;
  }
  zl2[tid] = acc;
}

// fused synthesis per (zo,b): stage 1 reads global directly (L2), 2 barriers
__global__ __launch_bounds__(256) void k_syn5(const float2* zl2, const float* dinv2,
                                              const int* psort, const int* npre,
                                              const float2* wsyn, const float* bias,
                                              float* out){
  __shared__ float2 Cs[NPAIR];               // 6.24 KB
  __shared__ __align__(16) float2 Gs[800];   // 6.4 KB
  __shared__ __align__(16) float2 Wns[1560]; // 12.48 KB
  __shared__ __align__(16) float2 Wms[800];  // 6.4 KB

  int bid = blockIdx.x;
  int blk = (bid & 7)*2560 + (bid >> 3);   // XCD-contiguous zo runs
  int b = blk % 40, zo = blk / 40;
  int o = zo & 31;
  int t = threadIdx.x;

  for (int idx = t; idx < 1560; idx += 256) Wns[idx] = wsyn[idx];
  for (int idx = t; idx < 800;  idx += 256) Wms[idx] = wsyn[1560+idx];

  // ---- stage 1: C[pair] = sum_l dinv2[b][k]*zl2[zo][k], direct global ----
  const float2* zrow = zl2 + (size_t)zo*NPACK;
  const float*  drow = dinv2 + (size_t)b*NPACK;
  int pk0 = psort[t], pk1 = psort[t+256];
  int pk2 = psort[(t+512<NPAIR)?(t+512):0];
  int pk3 = psort[(t+768<NPAIR)?(t+768):0];
  int mj0 = pk0&255, nj0 = (pk0>>8)&255;
  int mj1 = pk1&255, nj1 = (pk1>>8)&255;
  int mj2 = pk2&255, nj2 = (pk2>>8)&255;
  int mj3 = pk3&255, nj3 = (pk3>>8)&255;
  float2 c0 = make_float2(0.f,0.f), c1 = c0, c2 = c0, c3 = c0;

  #pragma unroll 4
  for (int l = 0; l < 20; ++l){
    int W = 2*l+1;
    int base = loffd(l) + l - 19;   // kidx = base + mj*W + njs
    int np = npre[l];
    if (t < np){
      int id = base + mj0*W + nj0;
      float dv = drow[id]; float2 zv = zrow[id];
      c0.x += dv*zv.x; c0.y += dv*zv.y;
    }
    if (t+256 < np){
      int id = base + mj1*W + nj1;
      float dv = drow[id]; float2 zv = zrow[id];
      c1.x += dv*zv.x; c1.y += dv*zv.y;
    }
    if (t+512 < np){
      int id = base + mj2*W + nj2;
      float dv = drow[id]; float2 zv = zrow[id];
      c2.x += dv*zv.x; c2.y += dv*zv.y;
    }
    if (t+768 < np){
      int id = base + mj3*W + nj3;
      float dv = drow[id]; float2 zv = zrow[id];
      c3.x += dv*zv.x; c3.y += dv*zv.y;
    }
  }
  Cs[mj0*39 + nj0] = c0;
  Cs[mj1*39 + nj1] = c1;
  if (t+512 < NPAIR) Cs[mj2*39 + nj2] = c2;
  if (t+768 < NPAIR) Cs[mj3*39 + nj3] = c3;
  __syncthreads();

  // ---- stage 2: G[mj][g] = sum_n C[mj][n] Wn[n][g], 2x2 tiles ----
  if (t < 200){
    int mj = 2*(t/20), g = 2*(t%20);
    float2 a00 = make_float2(0.f,0.f), a01 = a00, a10 = a00, a11 = a00;
    for (int nj = 0; nj < 39; ++nj){
      float2 cA = Cs[mj*39+nj], cB = Cs[(mj+1)*39+nj];
      float4 w = *(const float4*)&Wns[nj*40 + g];
      a00.x += cA.x*w.x - cA.y*w.y; a00.y += cA.x*w.y + cA.y*w.x;
      a01.x += cA.x*w.z - cA.y*w.w; a01.y += cA.x*w.w + cA.y*w.z;
      a10.x += cB.x*w.x - cB.y*w.y; a10.y += cB.x*w.y + cB.y*w.x;
      a11.x += cB.x*w.z - cB.y*w.w; a11.y += cB.x*w.w + cB.y*w.z;
    }
    *(float4*)&Gs[mj*40+g]     = make_float4(a00.x,a00.y,a01.x,a01.y);
    *(float4*)&Gs[(mj+1)*40+g] = make_float4(a10.x,a10.y,a11.x,a11.y);
  }
  __syncthreads();

  // ---- stage 3: out[a][g] = G0[g] + 2*sum_{mj>=1} Re(G*Wm) + bias ----
  if (t < 200){
    int a = 2*(t/10), g4 = 4*(t%10);
    float ac0[4] = {0.f,0.f,0.f,0.f};
    float ac1[4] = {0.f,0.f,0.f,0.f};
    for (int mj = 1; mj < 20; ++mj){
      float4 wm = *(const float4*)&Wms[mj*40 + a];
      float4 gA = *(const float4*)&Gs[mj*40 + g4];
      float4 gB = *(const float4*)&Gs[mj*40 + g4 + 2];
      ac0[0] += gA.x*wm.x - gA.y*wm.y;
      ac0[1] += gA.z*wm.x - gA.w*wm.y;
      ac0[2] += gB.x*wm.x - gB.y*wm.y;
      ac0[3] += gB.z*wm.x - gB.w*wm.y;
      ac1[0] += gA.x*wm.z - gA.y*wm.w;
      ac1[1] += gA.z*wm.z - gA.w*wm.w;
      ac1[2] += gB.x*wm.z - gB.y*wm.w;
      ac1[3] += gB.z*wm.z - gB.w*wm.w;
    }
    float4 G0a = *(const float4*)&Gs[g4];
    float4 G0b = *(const float4*)&Gs[g4+2];
    float bv = bias[o];
    float* orow = out + (size_t)blk*1600;
    float4 o0 = make_float4(G0a.x + 2.f*ac0[0] + bv, G0a.z + 2.f*ac0[1] + bv,
                            G0b.x + 2.f*ac0[2] + bv, G0b.z + 2.f*ac0[3] + bv);
    float4 o1 = make_float4(G0a.x + 2.f*ac1[0] + bv, G0a.z + 2.f*ac1[1] + bv,
                            G0b.x + 2.f*ac1[2] + bv, G0b.z + 2.f*ac1[3] + bv);
    *(float4*)(orow + a*40 + g4)     = o0;
    *(float4*)(orow + (a+1)*40 + g4) = o1;
  }
}

extern "C" void kernel_launch(void* const* d_in, const int* in_sizes, int n_in,
                              void* d_out, int out_size, void* d_ws, size_t ws_size,
                              hipStream_t stream) {
  const float* x    = (const float*)d_in[0];
  const float* ker  = (const float*)d_in[1];
  const float* bias = (const float*)d_in[2];
  float* out = (float*)d_out;

  char* ws = (char*)d_ws;
  size_t cur = 0;
  auto alloc = [&](size_t bytes)->char*{
    char* p = ws + cur;
    cur += (bytes + 255) & ~(size_t)255;
    return p;
  };
  double* lg    = (double*)alloc(64*8);
  double* wq    = (double*)alloc(128*8);
  int*    ridx  = (int*)   alloc(NPACK*4);
  int*    psort = (int*)   alloc(NPAIR*4);
  int*    npre  = (int*)   alloc(32*4);
  float2* wsyn  = (float2*)alloc((size_t)2360*8);
  float*  w_s2  = (float*) alloc((size_t)NB_IN*NLM*4);
  float*  dinv2 = (float*) alloc((size_t)TWOB*NPACK*4);
  float2* Fc    = (float2*)alloc((size_t)24*NLM*8);
  float2* ycT   = (float2*)alloc((size_t)512*400*8);
  float2* xf    = (float2*)alloc((size_t)NBINS*128*256*8);
  float2* xlp   = (float2*)alloc((size_t)4*NLM*256*8);
  float2* xlT   = (float2*)alloc((size_t)256*NLM*8);
  float2* zl2   = (float2*)alloc((size_t)NZO*NPACK*8);
  (void)ws_size; (void)in_sizes; (void)n_in; (void)out_size;

  k_init <<<1, 128, 0, stream>>>(lg, wq, ridx, psort, npre);
  k_wsyn <<<1, 256, 0, stream>>>(wsyn);
  k_ws2  <<<13, 256, 0, stream>>>(w_s2, lg, wq);
  k_dinv2<<<22, 256, 0, stream>>>(dinv2, ridx, lg);
  k_dmir <<<(20*NPACK + 255)/256, 256, 0, stream>>>(dinv2, ridx);
  k_Fc   <<<38, 256, 0, stream>>>(Fc, lg);
  k_yc   <<<800, 256, 0, stream>>>(ker, Fc, ycT);

  k_dft  <<<(256*128)/4, 256, 0, stream>>>(x, xf);
  k_xlp  <<<dim3(NLM, 4), 256, 0, stream>>>(xf, w_s2, xlp);
  k_xlsum<<<NLM, 256, 0, stream>>>(xlp, xlT);
  k_zl2  <<<(NZO*NPACK)/256, 256, 0, stream>>>(xlT, ycT, ridx, zl2);
  k_syn5 <<<NZO*TWOB, 256, 0, stream>>>(zl2, dinv2, psort, npre, wsyn, bias, out);
}

// Round 7
// 571.141 us; speedup vs baseline: 3.3422x; 1.4139x over previous
//
#include <hip/hip_runtime.h>
#include <math.h>

#define NB_IN   128
#define NBINS   39
#define NLM     400
#define NZO     512
#define NPAIR   780
#define NPACK   5530
#define TWOB    40
#define PI_D    3.14159265358979323846
#define SCALING 0.008164965809277261

__host__ __device__ __forceinline__ int loffd(int l){ return l*(4*l*l + 3*l - 1)/6; }

__device__ __forceinline__ int lidx(int lm){
  int l = (int)sqrtf((float)lm);
  while ((l+1)*(l+1) <= lm) ++l;
  while (l*l > lm) --l;
  return l;
}

// Wigner little-d via Jacobi sum (one-shot)
__device__ double wigner_d(int l, int m, int n, double beta, const double* lg){
  double cb = cos(0.5*beta), sb = sin(0.5*beta);
  double lcb = log(cb), lsb = log(sb);
  double pref = 0.5*(lg[l+m]+lg[l-m]+lg[l+n]+lg[l-n]);
  int s0 = 0 > (n-m) ? 0 : (n-m);
  int s1 = (l+n) < (l-m) ? (l+n) : (l-m);
  double val = 0.0;
  for (int s = s0; s <= s1; ++s){
    double c = pref - (lg[l+n-s]+lg[s]+lg[m-n+s]+lg[l-m-s]);
    double t = exp(c + (double)(2*l+n-m-2*s)*lcb + (double)(m-n+2*s)*lsb);
    val += ((m-n+s)&1) ? -t : t;
  }
  return val;
}

// fast Wigner: 2 log + 1 exp + ratio recurrence over s (fp64)
__device__ double wigner_fast(int l, int m, int n, double beta, const double* lg){
  double cb = cos(0.5*beta), sb = sin(0.5*beta);
  double lcb = log(cb), lsb = log(sb);
  double pref = 0.5*(lg[l+m]+lg[l-m]+lg[l+n]+lg[l-n]);
  int s0 = 0 > (n-m) ? 0 : (n-m);
  int s1 = (l+n) < (l-m) ? (l+n) : (l-m);
  double ratio = (sb*sb)/(cb*cb);
  double t = exp(pref - (lg[l+n-s0]+lg[s0]+lg[m-n+s0]+lg[l-m-s0])
               + (double)(2*l+n-m-2*s0)*lcb + (double)(m-n+2*s0)*lsb);
  double sgn = ((m-n+s0)&1) ? -1.0 : 1.0;
  double acc = 0.0;
  for (int s = s0; s <= s1; ++s){
    acc += sgn*t;
    sgn = -sgn;
    t *= ratio * ((double)((l+n-s)*(l-m-s)) / (double)((s+1)*(m-n+s+1)));
  }
  return acc;
}

// ---- constants -------------------------------------------------------
__global__ void k_init(double* lg, double* wq, int* ridx, int* psort){
  int t = threadIdx.x;  // 256
  if (t == 0){
    lg[0] = 0.0; double acc = 0.0;
    for (int k = 1; k <= 40; ++k){ acc += log((double)k); lg[k] = acc; }
  }
  // ridx: per (l,mj) pair, write its njs-run
  for (int pair = t; pair < 210; pair += 256){
    int l = (int)((sqrtf(8.f*pair+1.f)-1.f)*0.5f);
    while ((l+1)*(l+2)/2 <= pair) ++l;
    while (l*(l+1)/2 > pair) --l;
    int mj = pair - l*(l+1)/2;
    int base = loffd(l) + mj*(2*l+1);
    for (int j = 0; j < 2*l+1; ++j){
      int njs = 19-l + j;
      ridx[base+j] = mj | (njs<<8) | (l<<16);
    }
  }
  // psort: sorted-by-lmin ordering via closed-form rank
  for (int p = t; p < NPAIR; p += 256){
    int mj = p/39, njs = p%39, d = njs-19, ad = d<0?-d:d;
    int lam = mj > ad ? mj : ad;
    int pre = (lam==0) ? 0 : (2*lam-1)*lam;
    int rank = (mj < lam) ? (2*mj + ((njs==19+lam)?1:0))
                          : (2*lam + (njs-(19-lam)));
    psort[pre+rank] = mj | (njs<<8);
  }
  if (t < 128){
    double theta = PI_D*(2*t+1)/256.0;
    double s = 0.0;
    for (int k = 0; k < 64; ++k) s += sin((2*k+1)*theta)/(double)(2*k+1);
    wq[t] = (2.0/64.0)*sin(theta)*s;
  }
}

__global__ void k_wsyn(float2* wsyn){
  for (int idx = threadIdx.x; idx < 1560+800; idx += 256){
    double ang;
    if (idx < 1560){
      int njs = idx/40, g = idx%40;
      ang = 2.0*PI_D*(double)(njs-19)*(double)g/40.0;
    } else {
      int r = idx-1560; int mj = r/40, a = r%40;
      ang = 2.0*PI_D*(double)mj*(double)a/40.0;
    }
    wsyn[idx] = make_float2((float)cos(ang), (float)sin(ang));
  }
}

__global__ void k_ws2(float* w_s2, const double* lg, const double* wq){
  int tid = blockIdx.x*256 + threadIdx.x;
  if (tid >= 400*8) return;
  int lm = tid >> 3, bc = tid & 7;
  int l = lidx(lm); int m = lm - l*l - l;
  for (int j = 0; j < 16; ++j){
    int b = bc*16 + j;
    double beta = PI_D*(2*b+1)/256.0;
    w_s2[b*NLM + lm] = (float)(wigner_fast(l, m, 0, beta, lg) * wq[b]);
  }
}

__global__ void k_dinv2(float* dinv2, const int* ridx, const double* lg){
  int k = blockIdx.x*256 + threadIdx.x;
  if (k >= NPACK) return;
  int info = ridx[k];
  int mj = info & 255, n = ((info>>8)&255) - 19, l = info>>16;
  for (int b = 0; b < 20; ++b){
    double beta = PI_D*(2*b+1)/80.0;
    dinv2[b*NPACK + k] = (float)((double)(2*l+1) * wigner_fast(l, mj, n, beta, lg));
  }
}

__global__ void k_dmir(float* dinv2, const int* ridx){
  int tid = blockIdx.x*256 + threadIdx.x;
  if (tid >= 20*NPACK) return;
  int bb = tid / NPACK, k = tid % NPACK;
  int info = ridx[k];
  int mj = info & 255, njs = (info>>8)&255, l = info>>16;
  int srck = loffd(l) + mj*(2*l+1) + (l - (njs-19));
  float v = dinv2[(19-bb)*NPACK + srck];
  dinv2[(20+bb)*NPACK + k] = ((l+mj)&1) ? -v : v;
}

__global__ void k_Fc(float2* Fc, const double* lg){
  int tid = blockIdx.x*256 + threadIdx.x;
  if (tid >= 24*NLM) return;
  int p = tid / NLM, lm = tid % NLM;
  int l = lidx(lm); int m = lm - l*l - l;
  double beta = PI_D*(double)(p/8 + 1)/24.0;
  double alpha = (double)(p%8)*(PI_D/4.0);
  double d = wigner_d(l, m, 0, beta, lg);
  double a = (double)m*alpha;            // conj(F_k)
  Fc[tid] = make_float2((float)(d*cos(a)), (float)(d*sin(a)));
}

__global__ void k_yc(const float* ker, const float2* Fc, float2* ycT){
  int tid = blockIdx.x*256 + threadIdx.x;
  if (tid >= NLM*NZO) return;
  int lm = tid / 512, io = tid % 512;
  int i = io >> 5, o = io & 31;
  float2 acc = make_float2(0.f, 0.f);
  for (int p = 0; p < 24; ++p){
    float kv = ker[io*24 + p];
    float2 f = Fc[p*NLM + lm];
    acc.x += kv*f.x; acc.y += kv*f.y;
  }
  acc.x *= (float)SCALING; acc.y *= (float)SCALING;
  ycT[((size_t)(o*16 + i))*NLM + lm] = acc;
}

// ---- pipeline --------------------------------------------------------
__global__ __launch_bounds__(256) void k_dft(const float* x, float2* xf){
  __shared__ float rows[4][128];
  int t = threadIdx.x, g = t >> 6, lane = t & 63;
  int r = blockIdx.x*4 + g;
  int zi = r & 255, b = r >> 8;
  const float* xr = x + ((size_t)zi*128 + b)*128;
  rows[g][lane]    = xr[lane];
  rows[g][lane+64] = xr[lane+64];
  __syncthreads();
  if (lane < NBINS){
    int m = lane - 19;
    float ang = -2.0f*(float)PI_D*(float)m/128.0f;
    float sn, cs; sincosf(ang, &sn, &cs);
    float wr = 1.f, wi = 0.f;
    float2 acc = make_float2(0.f, 0.f);
    const float* rw = rows[g];
    #pragma unroll 8
    for (int a = 0; a < 128; ++a){
      float v = rw[a];
      acc.x += v*wr; acc.y += v*wi;
      float nr = wr*cs - wi*sn;
      wi = wr*sn + wi*cs; wr = nr;
    }
    xf[((size_t)lane*128 + b)*256 + zi] = acc;
  }
}

__global__ void k_xlp(const float2* xf, const float* w_s2, float2* xlp){
  int lm = blockIdx.x, c = blockIdx.y, zi = threadIdx.x;
  int l = lidx(lm); int m = lm - l*l - l;
  int bin = m + 19;
  float2 acc = make_float2(0.f, 0.f);
  for (int b = c*32; b < c*32+32; ++b){
    float w = w_s2[b*NLM + lm];
    float2 v = xf[((size_t)bin*128 + b)*256 + zi];
    acc.x += w*v.x; acc.y += w*v.y;
  }
  xlp[((size_t)(c*NLM + lm))*256 + zi] = acc;
}

__global__ void k_xlsum(const float2* xlp, float2* xlT){
  int lm = blockIdx.x, zi = threadIdx.x;
  float2 s = make_float2(0.f, 0.f);
  for (int c = 0; c < 4; ++c){
    float2 v = xlp[((size_t)(c*NLM + lm))*256 + zi];
    s.x += v.x; s.y += v.y;
  }
  xlT[(size_t)zi*NLM + lm] = s;
}

__global__ void k_zl2(const float2* xlT, const float2* ycT, const int* ridx, float2* zl2){
  int tid = blockIdx.x*256 + threadIdx.x;
  int zo = tid / NPACK, k = tid % NPACK;
  int info = ridx[k];
  int mj = info & 255, njs = (info>>8)&255, l = info>>16;
  int z = zo >> 5, o = zo & 31;
  int lmm = l*l + l + mj;
  int lmn = l*l + l + (njs - 19);
  float2 acc = make_float2(0.f, 0.f);
  for (int i = 0; i < 16; ++i){
    float2 a  = xlT[(size_t)(z*16 + i)*NLM + lmm];
    float2 bb = ycT[(size_t)(o*16 + i)*NLM + lmn];
    acc.x += a.x*bb.x - a.y*bb.y;
    acc.y += a.x*bb.y + a.y*bb.x;
  }
  zl2[tid] = acc;
}

// fused synthesis: block = (zo, 8 consecutive b), 512 threads
__global__ __launch_bounds__(512) void k_syn6(const float2* zl2, const float* dinv2,
                                              const int* psort, const float2* wsyn,
                                              const float* bias, float* out){
  __shared__ float2 zS[NPACK];               // 44.24 KB
  __shared__ float2 Cs[NPAIR];               // 6.24 KB
  __shared__ __align__(16) float2 Gs[800];   // 6.4 KB
  __shared__ __align__(16) float2 Wns[1560]; // 12.48 KB
  __shared__ __align__(16) float2 Wms[800];  // 6.4 KB

  int bid = blockIdx.x;
  int blk = (bid & 7)*320 + (bid >> 3);   // 2560 blocks, XCD-contiguous
  int zo = blk / 5, bgrp = blk % 5;
  int b0 = bgrp*8;
  int o = zo & 31;
  int t = threadIdx.x;

  // prologue: stage zl2 row + weights
  const float2* zrow = zl2 + (size_t)zo*NPACK;
  for (int k = t; k < NPACK; k += 512) zS[k] = zrow[k];
  for (int idx = t; idx < 1560; idx += 512) Wns[idx] = wsyn[idx];
  for (int idx = t; idx < 800;  idx += 512) Wms[idx] = wsyn[1560+idx];

  int pk0 = psort[t];
  int pk1 = psort[(t < NPAIR-512) ? (512+t) : 0];
  int mj0 = pk0&255, nj0 = (pk0>>8)&255;
  int mj1 = pk1&255, nj1 = (pk1>>8)&255;
  __syncthreads();

  float bv = bias[o];

  for (int bb = 0; bb < 8; ++bb){
    int b = b0 + bb;
    const float* drow = dinv2 + (size_t)b*NPACK;

    // ---- stage 1: C[pair] = sum_l d[b][id] * zS[id] ----
    float2 c0 = make_float2(0.f,0.f), c1 = c0;
    #pragma unroll
    for (int l = 0; l < 20; ++l){
      int W = 2*l+1;
      int base = loffd(l) + l - 19;     // id = base + mj*W + njs
      int np = (2*l+1)*(l+1);           // npre[l] closed form
      if (t < np){
        int id = base + mj0*W + nj0;
        float dv = drow[id]; float2 zv = zS[id];
        c0.x += dv*zv.x; c0.y += dv*zv.y;
      }
      if (512+t < np){
        int id = base + mj1*W + nj1;
        float dv = drow[id]; float2 zv = zS[id];
        c1.x += dv*zv.x; c1.y += dv*zv.y;
      }
    }
    Cs[mj0*39 + nj0] = c0;
    if (t < NPAIR-512) Cs[mj1*39 + nj1] = c1;
    __syncthreads();

    // ---- stage 2: G[mj][g] = sum_n C[mj][n] * Wn[n][g] ----
    // threads 0..199: g = t%40, mj-chunk = t/40 (4 mj each); Cs reads broadcast
    if (t < 200){
      int g = t % 40, mjc = t / 40;
      const float2* crow = Cs + (4*mjc)*39;
      float2 a0 = make_float2(0.f,0.f), a1 = a0, a2 = a0, a3 = a0;
      for (int nj = 0; nj < 39; ++nj){
        float2 w  = Wns[nj*40 + g];
        float2 cA = crow[nj];
        float2 cB = crow[39 + nj];
        float2 cC = crow[78 + nj];
        float2 cD = crow[117 + nj];
        a0.x += cA.x*w.x - cA.y*w.y; a0.y += cA.x*w.y + cA.y*w.x;
        a1.x += cB.x*w.x - cB.y*w.y; a1.y += cB.x*w.y + cB.y*w.x;
        a2.x += cC.x*w.x - cC.y*w.y; a2.y += cC.x*w.y + cC.y*w.x;
        a3.x += cD.x*w.x - cD.y*w.y; a3.y += cD.x*w.y + cD.y*w.x;
      }
      Gs[(4*mjc+0)*40 + g] = a0;
      Gs[(4*mjc+1)*40 + g] = a1;
      Gs[(4*mjc+2)*40 + g] = a2;
      Gs[(4*mjc+3)*40 + g] = a3;
    }
    __syncthreads();

    // ---- stage 3: out[a][g] = G0[g].x + 2*sum_{mj>=1} Re(G[mj][g]*Wm[mj][a]) + bias ----
    // threads 0..399: g = t%40, a-chunk = t/40 (4 a each); Wm reads broadcast
    if (t < 400){
      int g = t % 40, ac = t / 40;
      float s0 = 0.f, s1 = 0.f, s2 = 0.f, s3 = 0.f;
      for (int mj = 1; mj < 20; ++mj){
        float2 gv = Gs[mj*40 + g];
        float2 w0 = Wms[mj*40 + 4*ac+0];
        float2 w1 = Wms[mj*40 + 4*ac+1];
        float2 w2 = Wms[mj*40 + 4*ac+2];
        float2 w3 = Wms[mj*40 + 4*ac+3];
        s0 += gv.x*w0.x - gv.y*w0.y;
        s1 += gv.x*w1.x - gv.y*w1.y;
        s2 += gv.x*w2.x - gv.y*w2.y;
        s3 += gv.x*w3.x - gv.y*w3.y;
      }
      float g0 = Gs[g].x;
      float* orow = out + ((size_t)zo*40 + b)*1600;
      orow[(4*ac+0)*40 + g] = g0 + 2.f*s0 + bv;
      orow[(4*ac+1)*40 + g] = g0 + 2.f*s1 + bv;
      orow[(4*ac+2)*40 + g] = g0 + 2.f*s2 + bv;
      orow[(4*ac+3)*40 + g] = g0 + 2.f*s3 + bv;
    }
    // next bb's stage-1 Cs writes are safe: stage2 consumed Cs before last sync;
    // sync after next stage1 separates this stage3's Gs reads from next stage2's writes
  }
}

extern "C" void kernel_launch(void* const* d_in, const int* in_sizes, int n_in,
                              void* d_out, int out_size, void* d_ws, size_t ws_size,
                              hipStream_t stream) {
  const float* x    = (const float*)d_in[0];
  const float* ker  = (const float*)d_in[1];
  const float* bias = (const float*)d_in[2];
  float* out = (float*)d_out;

  char* ws = (char*)d_ws;
  size_t cur = 0;
  auto alloc = [&](size_t bytes)->char*{
    char* p = ws + cur;
    cur += (bytes + 255) & ~(size_t)255;
    return p;
  };
  double* lg    = (double*)alloc(64*8);
  double* wq    = (double*)alloc(128*8);
  int*    ridx  = (int*)   alloc(NPACK*4);
  int*    psort = (int*)   alloc(NPAIR*4);
  float2* wsyn  = (float2*)alloc((size_t)2360*8);
  float*  w_s2  = (float*) alloc((size_t)NB_IN*NLM*4);
  float*  dinv2 = (float*) alloc((size_t)TWOB*NPACK*4);
  float2* Fc    = (float2*)alloc((size_t)24*NLM*8);
  float2* ycT   = (float2*)alloc((size_t)512*400*8);
  float2* xf    = (float2*)alloc((size_t)NBINS*128*256*8);
  float2* xlp   = (float2*)alloc((size_t)4*NLM*256*8);
  float2* xlT   = (float2*)alloc((size_t)256*NLM*8);
  float2* zl2   = (float2*)alloc((size_t)NZO*NPACK*8);
  (void)ws_size; (void)in_sizes; (void)n_in; (void)out_size;

  k_init <<<1, 256, 0, stream>>>(lg, wq, ridx, psort);
  k_wsyn <<<1, 256, 0, stream>>>(wsyn);
  k_ws2  <<<13, 256, 0, stream>>>(w_s2, lg, wq);
  k_dinv2<<<22, 256, 0, stream>>>(dinv2, ridx, lg);
  k_dmir <<<(20*NPACK + 255)/256, 256, 0, stream>>>(dinv2, ridx);
  k_Fc   <<<38, 256, 0, stream>>>(Fc, lg);
  k_yc   <<<800, 256, 0, stream>>>(ker, Fc, ycT);

  k_dft  <<<(256*128)/4, 256, 0, stream>>>(x, xf);
  k_xlp  <<<dim3(NLM, 4), 256, 0, stream>>>(xf, w_s2, xlp);
  k_xlsum<<<NLM, 256, 0, stream>>>(xlp, xlT);
  k_zl2  <<<(NZO*NPACK)/256, 256, 0, stream>>>(xlT, ycT, ridx, zl2);
  k_syn6 <<<2560, 512, 0, stream>>>(zl2, dinv2, psort, wsyn, bias, out);
}